// Round 1
// baseline (118.688 us; speedup 1.0000x reference)
//
#include <hip/hip_runtime.h>
#include <stdint.h>

// Top-k (k=50) temperature sampling, bit-matching
// jax.random.categorical(key(42), topk_mask(logits/T, 50)) with
// jax_threefry_partitionable=True.
//
// Round-4 structure (one 1024-thread block per row, ONE data scan):
//   Hot pass: collect indices of elements with raw logit >= 10.0 (plain
//     float compare; division by positive T is monotone so raw order ==
//     scaled order). The 50th of 50257 N(0,16) draws sits at 12.36 +- 0.17,
//     so cutoff 10.0 captures the full top-50 with ~14-sigma margin while
//     collecting only ~312 candidates.
//   Refine (unchanged numerics): exact IEEE s = l/T keys, exact
//     (s_key, index) rank -> rank < K membership (lax.top_k low-index tie
//     rule), partitionable-threefry gumbel, argmax with low-index ties.
//   Exactness guards (both block-uniform, never trip on bench data):
//     (a) K <= count <= CAND_CAP  -> candidate set is a superset of top-K
//         (any non-candidate has s <= 10.0/T by monotone rounded division);
//     (b) the rank-(K-1) candidate's s-key must be STRICTLY > fkey(10.0/T)
//         so no sub-cutoff element can tie into top-K via a lower index.
//   If either guard fails: full original two-scan histogram path (verbatim
//   round-3 code) runs as fallback.

#define VOCAB 50257
#define BATCH 256
#define NT 1024
#define NBINS 4096
#define CAND_CAP 2048
#define FILTER_VAL 4.0f
#define SPEC_VAL 10.0f

__device__ __forceinline__ uint32_t rotl32(uint32_t v, int r) {
  return (v << r) | (v >> (32 - r));
}

// JAX Threefry-2x32-20, key = (0, 42)
__device__ __forceinline__ void threefry2x32_42(uint32_t& x0, uint32_t& x1) {
  const uint32_t ks0 = 0u;
  const uint32_t ks1 = 42u;
  const uint32_t ks2 = ks0 ^ ks1 ^ 0x1BD11BDAu;
  x0 += ks0; x1 += ks1;
#define TF_R(r) { x0 += x1; x1 = rotl32(x1, (r)); x1 ^= x0; }
  TF_R(13) TF_R(15) TF_R(26) TF_R(6)
  x0 += ks1; x1 += ks2 + 1u;
  TF_R(17) TF_R(29) TF_R(16) TF_R(24)
  x0 += ks2; x1 += ks0 + 2u;
  TF_R(13) TF_R(15) TF_R(26) TF_R(6)
  x0 += ks0; x1 += ks1 + 3u;
  TF_R(17) TF_R(29) TF_R(16) TF_R(24)
  x0 += ks1; x1 += ks2 + 4u;
  TF_R(13) TF_R(15) TF_R(26) TF_R(6)
  x0 += ks2; x1 += ks0 + 5u;
#undef TF_R
}

// Gumbel noise at flat index i, jax_threefry_partitionable=True:
// counter = u64 flat index -> (hi32=0, lo32=i), bits = out0 ^ out1.
__device__ __forceinline__ float gumbel_at(uint32_t flat) {
  uint32_t x0 = 0u, x1 = flat;
  threefry2x32_42(x0, x1);
  uint32_t bits = x0 ^ x1;
  uint32_t fb = (bits >> 9) | 0x3f800000u;
  float f = __uint_as_float(fb) - 1.0f;          // exact
  float u = fmaxf(f, 1.17549435e-38f);
  float t = (float)log((double)u);               // correctly-rounded fp32 path
  float g = (float)(-log((double)(-t)));
  return g;
}

// Monotone float->uint32 key (no NaNs in data).
__device__ __forceinline__ uint32_t fkey(float x) {
  uint32_t u = __float_as_uint(x);
  return (u & 0x80000000u) ? ~u : (u | 0x80000000u);
}

extern "C" __global__ void __launch_bounds__(NT)
topk_sample_kernel(const float* __restrict__ logits,
                   const float* __restrict__ temp_p,
                   const int* __restrict__ topk_p,
                   int* __restrict__ out) {
  const int row = blockIdx.x;
  const int tid = threadIdx.x;
  const float temp = temp_p[0];
  const int K = topk_p[0];
  const float* rowp = logits + (size_t)row * VOCAB;

  // rows are only 4B-aligned (VOCAB*4 % 16 == 4): scalar prologue to 16B.
  const int pc = (4 - (row & 3)) & 3;
  const int nv4 = (VOCAB - pc) >> 2;
  const int tailbase = pc + (nv4 << 2);
  const int tailc = VOCAB - tailbase;        // 0..3
  const float4* body = (const float4*)(rowp + pc);

  __shared__ unsigned hist[NBINS];
  __shared__ unsigned wtot[16];
  __shared__ unsigned aboveWave[16];
  __shared__ int sh_tb, sh_total, sh_cnt, sh_ok;
  __shared__ unsigned ckey[CAND_CAP];
  __shared__ int cidx[CAND_CAP];
  __shared__ float wbv[16];
  __shared__ int wbi[16];

  const int lane = tid & 63;
  const int wave = tid >> 6;

  float bestv = -__builtin_huge_valf();
  int besti = 0x7fffffff;
  bool done = false;

  // ---- Hot pass: single scan, speculative cutoff at SPEC_VAL ----
  if (tid == 0) { sh_cnt = 0; sh_ok = 0; }
  __syncthreads();
  if (tid < pc) {
    if (rowp[tid] >= SPEC_VAL) {
      int p = atomicAdd(&sh_cnt, 1);
      if (p < CAND_CAP) cidx[p] = tid;
    }
  }
  for (int v = tid; v < nv4; v += NT) {
    float4 x = body[v];
    int base = pc + (v << 2);
    if (x.x >= SPEC_VAL) { int p = atomicAdd(&sh_cnt, 1); if (p < CAND_CAP) cidx[p] = base; }
    if (x.y >= SPEC_VAL) { int p = atomicAdd(&sh_cnt, 1); if (p < CAND_CAP) cidx[p] = base + 1; }
    if (x.z >= SPEC_VAL) { int p = atomicAdd(&sh_cnt, 1); if (p < CAND_CAP) cidx[p] = base + 2; }
    if (x.w >= SPEC_VAL) { int p = atomicAdd(&sh_cnt, 1); if (p < CAND_CAP) cidx[p] = base + 3; }
  }
  if (tid < tailc) {
    if (rowp[tailbase + tid] >= SPEC_VAL) {
      int p = atomicAdd(&sh_cnt, 1);
      if (p < CAND_CAP) cidx[p] = tailbase + tid;
    }
  }
  __syncthreads();
  const int total = sh_cnt;                  // block-uniform

  if (total >= K && total <= CAND_CAP) {     // guard (a): superset of top-K
    const int C = total;
    float s_mine = 0.0f;
    if (tid < C) {
      s_mine = rowp[cidx[tid]] / temp;       // IEEE fp32 div, matches reference
      ckey[tid] = fkey(s_mine);
    }
    __syncthreads();
    if (tid < C) {
      const uint32_t mk = ckey[tid];
      const int mi = cidx[tid];
      int rank = 0;
      for (int j = 0; j < C; ++j) {
        uint32_t k = ckey[j];
        rank += (k > mk || (k == mk && cidx[j] < mi)) ? 1 : 0;
      }
      if (rank == K - 1) {
        // guard (b): K-th s-key strictly above the cutoff's s-key =>
        // no element below SPEC_VAL can reach or tie the top-K boundary.
        sh_ok = (mk > fkey(SPEC_VAL / temp)) ? 1 : 0;
      }
      if (rank < K) {                        // exact lax.top_k membership
        float v = s_mine + gumbel_at((uint32_t)row * (uint32_t)VOCAB + (uint32_t)mi);
        bestv = v; besti = mi;
      }
    }
    __syncthreads();
    if (sh_ok) {
      done = true;                           // block-uniform
    } else {
      bestv = -__builtin_huge_valf();        // discard, take fallback
      besti = 0x7fffffff;
    }
  }

  // ---- Fallback: original round-3 two-scan histogram path (never taken
  //      on bench data; exact for arbitrary inputs). ----
  if (!done) {
    uint32_t filt = fkey(FILTER_VAL);
    int tb = 0;
    for (;;) {
      for (int b = tid; b < NBINS; b += NT) hist[b] = 0u;
      __syncthreads();
      if (tid < pc) {
        uint32_t k = fkey(rowp[tid]);
        if (k >= filt) atomicAdd(&hist[k >> 20], 1u);
      }
      for (int v = tid; v < nv4; v += NT) {
        float4 x = body[v];
        uint32_t k0 = fkey(x.x), k1 = fkey(x.y), k2 = fkey(x.z), k3 = fkey(x.w);
        if (k0 >= filt) atomicAdd(&hist[k0 >> 20], 1u);
        if (k1 >= filt) atomicAdd(&hist[k1 >> 20], 1u);
        if (k2 >= filt) atomicAdd(&hist[k2 >> 20], 1u);
        if (k3 >= filt) atomicAdd(&hist[k3 >> 20], 1u);
      }
      if (tid < tailc) {
        uint32_t k = fkey(rowp[tailbase + tid]);
        if (k >= filt) atomicAdd(&hist[k >> 20], 1u);
      }
      __syncthreads();

      unsigned p = hist[4 * tid] + hist[4 * tid + 1] + hist[4 * tid + 2] + hist[4 * tid + 3];
      unsigned v = p;
      for (int off = 1; off < 64; off <<= 1) {
        unsigned o = (unsigned)__shfl_down((int)v, off);
        if (lane + off < 64) v += o;       // inclusive suffix sum within wave
      }
      if (lane == 0) wtot[wave] = v;
      __syncthreads();
      if (tid == 0) {
        unsigned acc = 0;
        for (int w = 15; w >= 0; --w) { aboveWave[w] = acc; acc += wtot[w]; }
        sh_total = (int)acc;
      }
      __syncthreads();
      unsigned above = aboveWave[wave] + (v - p);
      if (above < (unsigned)K && above + p >= (unsigned)K) {
        int need = K - (int)above;
        for (int b = 3; b >= 0; --b) {
          unsigned c = hist[4 * tid + b];
          if (c >= (unsigned)need) { sh_tb = 4 * tid + b; break; }
          need -= (int)c;
        }
      }
      __syncthreads();
      if (sh_total >= K) { tb = sh_tb; break; }
      filt = 0u;
      __syncthreads();
    }

    const uint32_t cutk = (uint32_t)max(tb - 1, 0) << 20;
    if (tid == 0) sh_cnt = 0;
    __syncthreads();
    if (tid < pc) {
      if (fkey(rowp[tid]) >= cutk) {
        int p = atomicAdd(&sh_cnt, 1);
        if (p < CAND_CAP) cidx[p] = tid;
      }
    }
    for (int v = tid; v < nv4; v += NT) {
      float4 x = body[v];
      int base = pc + (v << 2);
      if (fkey(x.x) >= cutk) { int p = atomicAdd(&sh_cnt, 1); if (p < CAND_CAP) cidx[p] = base; }
      if (fkey(x.y) >= cutk) { int p = atomicAdd(&sh_cnt, 1); if (p < CAND_CAP) cidx[p] = base + 1; }
      if (fkey(x.z) >= cutk) { int p = atomicAdd(&sh_cnt, 1); if (p < CAND_CAP) cidx[p] = base + 2; }
      if (fkey(x.w) >= cutk) { int p = atomicAdd(&sh_cnt, 1); if (p < CAND_CAP) cidx[p] = base + 3; }
    }
    if (tid < tailc) {
      if (fkey(rowp[tailbase + tid]) >= cutk) {
        int p = atomicAdd(&sh_cnt, 1);
        if (p < CAND_CAP) cidx[p] = tailbase + tid;
      }
    }
    __syncthreads();
    const int C = min(sh_cnt, CAND_CAP);

    if (tid < C) {
      int idx = cidx[tid];
      float s = rowp[idx] / temp;
      ckey[tid] = fkey(s);
    }
    __syncthreads();

    if (tid < C) {
      const uint32_t mk = ckey[tid];
      const int mi = cidx[tid];
      int rank = 0;
      for (int j = 0; j < C; ++j) {
        uint32_t k = ckey[j];
        rank += (k > mk || (k == mk && cidx[j] < mi)) ? 1 : 0;
      }
      if (rank < K) {
        float s = rowp[mi] / temp;
        float v = s + gumbel_at((uint32_t)row * (uint32_t)VOCAB + (uint32_t)mi);
        bestv = v; besti = mi;
      }
    }
    __syncthreads();
  }

  // ---- Common argmax reduction: wave shuffle + 16-way LDS combine ----
  for (int off = 32; off > 0; off >>= 1) {
    float v2 = __shfl_down(bestv, off);
    int i2 = __shfl_down(besti, off);
    if (v2 > bestv || (v2 == bestv && i2 < besti)) { bestv = v2; besti = i2; }
  }
  if (lane == 0) { wbv[wave] = bestv; wbi[wave] = besti; }
  __syncthreads();
  if (tid == 0) {
    float bv = wbv[0];
    int bi = wbi[0];
    for (int w = 1; w < 16; ++w) {
      float v2 = wbv[w];
      int i2 = wbi[w];
      if (v2 > bv || (v2 == bv && i2 < bi)) { bv = v2; bi = i2; }
    }
    out[row] = bi;
  }
}

extern "C" void kernel_launch(void* const* d_in, const int* in_sizes, int n_in,
                              void* d_out, int out_size, void* d_ws, size_t ws_size,
                              hipStream_t stream) {
  const float* logits = (const float*)d_in[0];
  const float* temp_p = (const float*)d_in[1];
  const int* topk_p = (const int*)d_in[2];
  int* out = (int*)d_out;
  hipLaunchKernelGGL(topk_sample_kernel, dim3(BATCH), dim3(NT), 0, stream,
                     logits, temp_p, topk_p, out);
}

// Round 3
// 114.487 us; speedup vs baseline: 1.0367x; 1.0367x over previous
//
#include <hip/hip_runtime.h>
#include <stdint.h>

// Top-k (k=50) temperature sampling, bit-matching
// jax.random.categorical(key(42), topk_mask(logits/T, 50)) with
// jax_threefry_partitionable=True.
//
// Round-6 = round-5 with the PROC4 macro-parameter capture bug fixed
// (parameter was named `x`, so `x.x` expanded to `x1.x1` for argument x1).
//
// Structure (one 1024-thread block per row, ONE data scan, 4-wide
// load batching for memory-level parallelism):
//   Hot pass: collect indices of elements with raw logit >= 10.0 (plain
//     float compare; division by positive T is monotone so raw order ==
//     scaled order). The 50th of 50257 N(0,16) draws sits at 12.36 +- 0.17,
//     so cutoff 10.0 captures the full top-50 with ~14-sigma margin while
//     collecting only ~312 candidates.
//     Loads are issued 4 x float4 per thread per group (3 full groups + <=1
//     remainder) so each wave keeps 4 KB in flight instead of serializing
//     ~13 dependent HBM latencies (round-4 was latency-bound: 563 GB/s,
//     VALUBusy 12%).
//   Refine (unchanged numerics): exact IEEE s = l/T keys, exact
//     (s_key, index) rank -> rank < K membership (lax.top_k low-index tie
//     rule), partitionable-threefry gumbel, argmax with low-index ties.
//   Exactness guards (both block-uniform, never trip on bench data):
//     (a) K <= count <= CAND_CAP  -> candidate set is a superset of top-K
//         (any non-candidate has s <= 10.0/T by monotone rounded division);
//     (b) the rank-(K-1) candidate's s-key must be STRICTLY > fkey(10.0/T)
//         so no sub-cutoff element can tie into top-K via a lower index.
//   If either guard fails: full original two-scan histogram path (verbatim
//   round-3 code) runs as fallback.

#define VOCAB 50257
#define BATCH 256
#define NT 1024
#define NBINS 4096
#define CAND_CAP 2048
#define FILTER_VAL 4.0f
#define SPEC_VAL 10.0f

__device__ __forceinline__ uint32_t rotl32(uint32_t v, int r) {
  return (v << r) | (v >> (32 - r));
}

// JAX Threefry-2x32-20, key = (0, 42)
__device__ __forceinline__ void threefry2x32_42(uint32_t& x0, uint32_t& x1) {
  const uint32_t ks0 = 0u;
  const uint32_t ks1 = 42u;
  const uint32_t ks2 = ks0 ^ ks1 ^ 0x1BD11BDAu;
  x0 += ks0; x1 += ks1;
#define TF_R(r) { x0 += x1; x1 = rotl32(x1, (r)); x1 ^= x0; }
  TF_R(13) TF_R(15) TF_R(26) TF_R(6)
  x0 += ks1; x1 += ks2 + 1u;
  TF_R(17) TF_R(29) TF_R(16) TF_R(24)
  x0 += ks2; x1 += ks0 + 2u;
  TF_R(13) TF_R(15) TF_R(26) TF_R(6)
  x0 += ks0; x1 += ks1 + 3u;
  TF_R(17) TF_R(29) TF_R(16) TF_R(24)
  x0 += ks1; x1 += ks2 + 4u;
  TF_R(13) TF_R(15) TF_R(26) TF_R(6)
  x0 += ks2; x1 += ks0 + 5u;
#undef TF_R
}

// Gumbel noise at flat index i, jax_threefry_partitionable=True:
// counter = u64 flat index -> (hi32=0, lo32=i), bits = out0 ^ out1.
__device__ __forceinline__ float gumbel_at(uint32_t flat) {
  uint32_t x0 = 0u, x1 = flat;
  threefry2x32_42(x0, x1);
  uint32_t bits = x0 ^ x1;
  uint32_t fb = (bits >> 9) | 0x3f800000u;
  float f = __uint_as_float(fb) - 1.0f;          // exact
  float u = fmaxf(f, 1.17549435e-38f);
  float t = (float)log((double)u);               // correctly-rounded fp32 path
  float g = (float)(-log((double)(-t)));
  return g;
}

// Monotone float->uint32 key (no NaNs in data).
__device__ __forceinline__ uint32_t fkey(float x) {
  uint32_t u = __float_as_uint(x);
  return (u & 0x80000000u) ? ~u : (u | 0x80000000u);
}

extern "C" __global__ void __launch_bounds__(NT)
topk_sample_kernel(const float* __restrict__ logits,
                   const float* __restrict__ temp_p,
                   const int* __restrict__ topk_p,
                   int* __restrict__ out) {
  const int row = blockIdx.x;
  const int tid = threadIdx.x;
  const float temp = temp_p[0];
  const int K = topk_p[0];
  const float* rowp = logits + (size_t)row * VOCAB;

  // rows are only 4B-aligned (VOCAB*4 % 16 == 4): scalar prologue to 16B.
  const int pc = (4 - (row & 3)) & 3;
  const int nv4 = (VOCAB - pc) >> 2;
  const int tailbase = pc + (nv4 << 2);
  const int tailc = VOCAB - tailbase;        // 0..3
  const float4* body = (const float4*)(rowp + pc);

  __shared__ unsigned hist[NBINS];
  __shared__ unsigned wtot[16];
  __shared__ unsigned aboveWave[16];
  __shared__ int sh_tb, sh_total, sh_cnt, sh_ok;
  __shared__ unsigned ckey[CAND_CAP];
  __shared__ int cidx[CAND_CAP];
  __shared__ float wbv[16];
  __shared__ int wbi[16];

  const int lane = tid & 63;
  const int wave = tid >> 6;

  float bestv = -__builtin_huge_valf();
  int besti = 0x7fffffff;
  bool done = false;

  // ---- Hot pass: single scan, speculative cutoff at SPEC_VAL ----
  if (tid == 0) { sh_cnt = 0; sh_ok = 0; }
  __syncthreads();
  if (tid < pc) {
    if (rowp[tid] >= SPEC_VAL) {
      int p = atomicAdd(&sh_cnt, 1);
      if (p < CAND_CAP) cidx[p] = tid;
    }
  }
  // 4-wide batched scan: issue 4 independent dwordx4 loads, then process 16
  // elements. nv4 ~= 12564, NT=1024 -> exactly 3 full groups + <=1 remainder.
  int v = tid;
  for (; v + 3 * NT < nv4; v += 4 * NT) {
    float4 x0 = body[v];
    float4 x1 = body[v + NT];
    float4 x2 = body[v + 2 * NT];
    float4 x3 = body[v + 3 * NT];
#define PROC4(VX, b)                                                             \
    {                                                                            \
      int base_ = (b);                                                           \
      if (VX.x >= SPEC_VAL) { int p = atomicAdd(&sh_cnt, 1); if (p < CAND_CAP) cidx[p] = base_; }     \
      if (VX.y >= SPEC_VAL) { int p = atomicAdd(&sh_cnt, 1); if (p < CAND_CAP) cidx[p] = base_ + 1; } \
      if (VX.z >= SPEC_VAL) { int p = atomicAdd(&sh_cnt, 1); if (p < CAND_CAP) cidx[p] = base_ + 2; } \
      if (VX.w >= SPEC_VAL) { int p = atomicAdd(&sh_cnt, 1); if (p < CAND_CAP) cidx[p] = base_ + 3; } \
    }
    PROC4(x0, pc + (v << 2))
    PROC4(x1, pc + ((v + NT) << 2))
    PROC4(x2, pc + ((v + 2 * NT) << 2))
    PROC4(x3, pc + ((v + 3 * NT) << 2))
  }
  for (; v < nv4; v += NT) {
    float4 x = body[v];
    PROC4(x, pc + (v << 2))
  }
#undef PROC4
  if (tid < tailc) {
    if (rowp[tailbase + tid] >= SPEC_VAL) {
      int p = atomicAdd(&sh_cnt, 1);
      if (p < CAND_CAP) cidx[p] = tailbase + tid;
    }
  }
  __syncthreads();
  const int total = sh_cnt;                  // block-uniform

  if (total >= K && total <= CAND_CAP) {     // guard (a): superset of top-K
    const int C = total;
    float s_mine = 0.0f;
    if (tid < C) {
      s_mine = rowp[cidx[tid]] / temp;       // IEEE fp32 div, matches reference
      ckey[tid] = fkey(s_mine);
    }
    __syncthreads();
    if (tid < C) {
      const uint32_t mk = ckey[tid];
      const int mi = cidx[tid];
      int rank = 0;
      for (int j = 0; j < C; ++j) {
        uint32_t k = ckey[j];
        rank += (k > mk || (k == mk && cidx[j] < mi)) ? 1 : 0;
      }
      if (rank == K - 1) {
        // guard (b): K-th s-key strictly above the cutoff's s-key =>
        // no element below SPEC_VAL can reach or tie the top-K boundary.
        sh_ok = (mk > fkey(SPEC_VAL / temp)) ? 1 : 0;
      }
      if (rank < K) {                        // exact lax.top_k membership
        float v2 = s_mine + gumbel_at((uint32_t)row * (uint32_t)VOCAB + (uint32_t)mi);
        bestv = v2; besti = mi;
      }
    }
    __syncthreads();
    if (sh_ok) {
      done = true;                           // block-uniform
    } else {
      bestv = -__builtin_huge_valf();        // discard, take fallback
      besti = 0x7fffffff;
    }
  }

  // ---- Fallback: original round-3 two-scan histogram path (never taken
  //      on bench data; exact for arbitrary inputs). ----
  if (!done) {
    uint32_t filt = fkey(FILTER_VAL);
    int tb = 0;
    for (;;) {
      for (int b = tid; b < NBINS; b += NT) hist[b] = 0u;
      __syncthreads();
      if (tid < pc) {
        uint32_t k = fkey(rowp[tid]);
        if (k >= filt) atomicAdd(&hist[k >> 20], 1u);
      }
      for (int w = tid; w < nv4; w += NT) {
        float4 x = body[w];
        uint32_t k0 = fkey(x.x), k1 = fkey(x.y), k2 = fkey(x.z), k3 = fkey(x.w);
        if (k0 >= filt) atomicAdd(&hist[k0 >> 20], 1u);
        if (k1 >= filt) atomicAdd(&hist[k1 >> 20], 1u);
        if (k2 >= filt) atomicAdd(&hist[k2 >> 20], 1u);
        if (k3 >= filt) atomicAdd(&hist[k3 >> 20], 1u);
      }
      if (tid < tailc) {
        uint32_t k = fkey(rowp[tailbase + tid]);
        if (k >= filt) atomicAdd(&hist[k >> 20], 1u);
      }
      __syncthreads();

      unsigned p = hist[4 * tid] + hist[4 * tid + 1] + hist[4 * tid + 2] + hist[4 * tid + 3];
      unsigned vv = p;
      for (int off = 1; off < 64; off <<= 1) {
        unsigned o = (unsigned)__shfl_down((int)vv, off);
        if (lane + off < 64) vv += o;      // inclusive suffix sum within wave
      }
      if (lane == 0) wtot[wave] = vv;
      __syncthreads();
      if (tid == 0) {
        unsigned acc = 0;
        for (int w = 15; w >= 0; --w) { aboveWave[w] = acc; acc += wtot[w]; }
        sh_total = (int)acc;
      }
      __syncthreads();
      unsigned above = aboveWave[wave] + (vv - p);
      if (above < (unsigned)K && above + p >= (unsigned)K) {
        int need = K - (int)above;
        for (int b = 3; b >= 0; --b) {
          unsigned c = hist[4 * tid + b];
          if (c >= (unsigned)need) { sh_tb = 4 * tid + b; break; }
          need -= (int)c;
        }
      }
      __syncthreads();
      if (sh_total >= K) { tb = sh_tb; break; }
      filt = 0u;
      __syncthreads();
    }

    const uint32_t cutk = (uint32_t)max(tb - 1, 0) << 20;
    if (tid == 0) sh_cnt = 0;
    __syncthreads();
    if (tid < pc) {
      if (fkey(rowp[tid]) >= cutk) {
        int p = atomicAdd(&sh_cnt, 1);
        if (p < CAND_CAP) cidx[p] = tid;
      }
    }
    for (int w = tid; w < nv4; w += NT) {
      float4 x = body[w];
      int base = pc + (w << 2);
      if (fkey(x.x) >= cutk) { int p = atomicAdd(&sh_cnt, 1); if (p < CAND_CAP) cidx[p] = base; }
      if (fkey(x.y) >= cutk) { int p = atomicAdd(&sh_cnt, 1); if (p < CAND_CAP) cidx[p] = base + 1; }
      if (fkey(x.z) >= cutk) { int p = atomicAdd(&sh_cnt, 1); if (p < CAND_CAP) cidx[p] = base + 2; }
      if (fkey(x.w) >= cutk) { int p = atomicAdd(&sh_cnt, 1); if (p < CAND_CAP) cidx[p] = base + 3; }
    }
    if (tid < tailc) {
      if (fkey(rowp[tailbase + tid]) >= cutk) {
        int p = atomicAdd(&sh_cnt, 1);
        if (p < CAND_CAP) cidx[p] = tailbase + tid;
      }
    }
    __syncthreads();
    const int C = min(sh_cnt, CAND_CAP);

    if (tid < C) {
      int idx = cidx[tid];
      float s = rowp[idx] / temp;
      ckey[tid] = fkey(s);
    }
    __syncthreads();

    if (tid < C) {
      const uint32_t mk = ckey[tid];
      const int mi = cidx[tid];
      int rank = 0;
      for (int j = 0; j < C; ++j) {
        uint32_t k = ckey[j];
        rank += (k > mk || (k == mk && cidx[j] < mi)) ? 1 : 0;
      }
      if (rank < K) {
        float s = rowp[mi] / temp;
        float v2 = s + gumbel_at((uint32_t)row * (uint32_t)VOCAB + (uint32_t)mi);
        bestv = v2; besti = mi;
      }
    }
    __syncthreads();
  }

  // ---- Common argmax reduction: wave shuffle + 16-way LDS combine ----
  for (int off = 32; off > 0; off >>= 1) {
    float v2 = __shfl_down(bestv, off);
    int i2 = __shfl_down(besti, off);
    if (v2 > bestv || (v2 == bestv && i2 < besti)) { bestv = v2; besti = i2; }
  }
  if (lane == 0) { wbv[wave] = bestv; wbi[wave] = besti; }
  __syncthreads();
  if (tid == 0) {
    float bv = wbv[0];
    int bi = wbi[0];
    for (int w = 1; w < 16; ++w) {
      float v2 = wbv[w];
      int i2 = wbi[w];
      if (v2 > bv || (v2 == bv && i2 < bi)) { bv = v2; bi = i2; }
    }
    out[row] = bi;
  }
}

extern "C" void kernel_launch(void* const* d_in, const int* in_sizes, int n_in,
                              void* d_out, int out_size, void* d_ws, size_t ws_size,
                              hipStream_t stream) {
  const float* logits = (const float*)d_in[0];
  const float* temp_p = (const float*)d_in[1];
  const int* topk_p = (const int*)d_in[2];
  int* out = (int*)d_out;
  hipLaunchKernelGGL(topk_sample_kernel, dim3(BATCH), dim3(NT), 0, stream,
                     logits, temp_p, topk_p, out);
}